// Round 8
// baseline (82.508 us; speedup 1.0000x reference)
//
#include <hip/hip_runtime.h>
#include <math.h>

// AttentionContextEncoder on MI355X — R8: h-split (2 blocks/batch), A-frags
// in registers, 2 barriers, Horner epilogue.  Math identical to R7:
// tanh3(x)=x+C3*x^3, x = a_i - p_j + w4*d_ij; sum_j x^3 via moments + three
// bf16 MFMA GEMMs (M_a = d@P, M_b = d@P^2, M_c = d^2@P) per (batch, h-half).

#define NUM_ENT 64
#define HALF    128
#define HHALF   64      // h's per block
#define NI      4       // 16-wide n-tiles per block
#define BATCH   512
#define ROWP    72      // ushort stride (144 B = 9*16)

typedef short s16x8 __attribute__((ext_vector_type(8)));
typedef float f32x4 __attribute__((ext_vector_type(4)));

__device__ __forceinline__ unsigned short f2bf(float f) {
    union { float f; unsigned u; } c; c.f = f;
    return (unsigned short)((c.u + 0x7fffu + ((c.u >> 16) & 1u)) >> 16);
}
__device__ __forceinline__ float tanh5(float x) {
    float x2 = x * x;
    return x * fmaf(x2, fmaf(x2, 0.13333334f, -0.33333334f), 1.0f);
}

__global__ __launch_bounds__(256, 4) void fused_enc(
    const float* __restrict__ ctx, const float* __restrict__ Wp,
    const float* __restrict__ bp,  const float* __restrict__ Wr,
    const float* __restrict__ br,  float* __restrict__ out)
{
    __shared__ __align__(16) float se[NUM_ENT * 4];           // entities
    __shared__ float sW[11][HHALF];                           // w0..4,bb,q0..3,bq
    __shared__ __align__(16) unsigned short sPT [HHALF][ROWP]; // P^T   bf16
    __shared__ __align__(16) unsigned short sPT2[HHALF][ROWP]; // (P²)^T
    __shared__ float sD1[NUM_ENT], sD2[NUM_ENT], sD3[NUM_ENT];
    __shared__ float sEsum[4];
    __shared__ float sP2p[4][HHALF], sP3p[4][HHALF];

    const int t     = threadIdx.x;
    const int b     = blockIdx.x >> 1;
    const int hbase = (blockIdx.x & 1) * HHALF;
    const int lane  = t & 63;
    const int wv    = t >> 6;

    // ---- stage entities (column b) + this half's weights ----
    se[t] = ctx[(size_t)t * BATCH + b];
    if (t < HHALF) {
        int h = hbase + t;
        sW[0][t] = Wr[h];          sW[1][t] = Wr[HALF + h];
        sW[2][t] = Wr[2*HALF + h]; sW[3][t] = Wr[3*HALF + h];
        sW[4][t] = Wr[4*HALF + h]; sW[5][t] = br[h];
        sW[6][t] = Wp[h];          sW[7][t] = Wp[HALF + h];
        sW[8][t] = Wp[2*HALF + h]; sW[9][t] = Wp[3*HALF + h];
        sW[10][t] = bp[h];
    }
    __syncthreads();

    // ---- A-fragments (d, d^2 bf16) directly in MFMA layout + D moments ----
    const int m = lane & 15, quad = lane >> 4;
    const int i0 = wv * 16 + m;
    const float4 ei = ((const float4*)se)[i0];
    unsigned short da[16], d2a[16];
    float d1s = 0.f, d2s = 0.f, d3s = 0.f;
    #pragma unroll
    for (int g = 0; g < 2; ++g) {
        #pragma unroll
        for (int jj = 0; jj < 8; ++jj) {
            int j = g * 32 + quad * 8 + jj;       // A[m][k]: k = quad*8+jj
            float4 ej = ((const float4*)se)[j];   // uniform in quad
            float dx = ei.x - ej.x, dy = ei.y - ej.y;
            float d2 = fmaf(dx, dx, dy * dy);
            float d  = sqrtf(d2);                 // exact 0 at j==i0
            da [g*8+jj] = f2bf(d);
            d2a[g*8+jj] = f2bf(d2);
            d1s += d; d2s += d2; d3s = fmaf(d, d2, d3s);
        }
    }
    d1s += __shfl_xor(d1s, 16); d1s += __shfl_xor(d1s, 32);
    d2s += __shfl_xor(d2s, 16); d2s += __shfl_xor(d2s, 32);
    d3s += __shfl_xor(d3s, 16); d3s += __shfl_xor(d3s, 32);
    if (quad == 0) { sD1[i0] = d1s; sD2[i0] = d2s; sD3[i0] = d3s; }

    // ---- Esum (for exact P1 = Esum . w_h) ----
    if (t < 64) {
        float4 e = ((const float4*)se)[t];
        float ex = e.x, ey = e.y, ez = e.z, ew = e.w;
        #pragma unroll
        for (int s = 1; s < 64; s <<= 1) {
            ex += __shfl_xor(ex, s); ey += __shfl_xor(ey, s);
            ez += __shfl_xor(ez, s); ew += __shfl_xor(ew, s);
        }
        if (t == 0) { sEsum[0]=ex; sEsum[1]=ey; sEsum[2]=ez; sEsum[3]=ew; }
    }

    // ---- P^T, (P^2)^T: wave wv covers 16 h's, lane = j ----
    {
        const float4 ejl = ((const float4*)se)[lane];
        #pragma unroll
        for (int hh = 0; hh < 16; ++hh) {
            int hl = wv * 16 + hh;                // wave-uniform
            float p = fmaf(ejl.x, sW[0][hl], fmaf(ejl.y, sW[1][hl],
                      fmaf(ejl.z, sW[2][hl], ejl.w * sW[3][hl])));
            sPT [hl][lane] = f2bf(p);
            sPT2[hl][lane] = f2bf(p * p);
        }
    }

    // ---- P2/P3 partials (fp32, from se directly) ----
    {
        const int hl = t & 63, part = t >> 6;
        const float w0 = sW[0][hl], w1 = sW[1][hl];
        const float w2 = sW[2][hl], w3 = sW[3][hl];
        float s2 = 0.f, s3 = 0.f;
        #pragma unroll
        for (int jj = 0; jj < 16; ++jj) {
            float4 e = ((const float4*)se)[part * 16 + jj];
            float p = fmaf(e.x, w0, fmaf(e.y, w1, fmaf(e.z, w2, e.w * w3)));
            float p2 = p * p;
            s2 += p2; s3 = fmaf(p, p2, s3);
        }
        sP2p[part][hl] = s2; sP3p[part][hl] = s3;
    }
    __syncthreads();

    // ---- MFMA moments + fused epilogue ----
    {
        const int n15 = m;
        const s16x8 afd0  = *(const s16x8*)&da[0];
        const s16x8 afd1  = *(const s16x8*)&da[8];
        const s16x8 afd20 = *(const s16x8*)&d2a[0];
        const s16x8 afd21 = *(const s16x8*)&d2a[8];

        const float Ex = sEsum[0], Ey = sEsum[1], Ez = sEsum[2], Ew = sEsum[3];
        const float C3 = -0.33333334f;

        // hoist per-row (r) data
        float D1r[4], D2r[4], D3r[4];
        float4 er[4];
        #pragma unroll
        for (int r = 0; r < 4; ++r) {
            int i = wv * 16 + quad * 4 + r;       // C-layout row
            D1r[r] = sD1[i]; D2r[r] = sD2[i]; D3r[r] = sD3[i];
            er[r] = ((const float4*)se)[i];
        }

        #pragma unroll
        for (int ni = 0; ni < NI; ++ni) {
            const int hl = ni * 16 + n15;
            s16x8 bp0 = *(const s16x8*)&sPT [hl][quad * 8];
            s16x8 bp1 = *(const s16x8*)&sPT [hl][32 + quad * 8];
            s16x8 bq0 = *(const s16x8*)&sPT2[hl][quad * 8];
            s16x8 bq1 = *(const s16x8*)&sPT2[hl][32 + quad * 8];
            f32x4 Ma = {0.f,0.f,0.f,0.f}, Mb = {0.f,0.f,0.f,0.f},
                  Mc = {0.f,0.f,0.f,0.f};
            Ma = __builtin_amdgcn_mfma_f32_16x16x32_bf16(afd0,  bp0, Ma, 0,0,0);
            Ma = __builtin_amdgcn_mfma_f32_16x16x32_bf16(afd1,  bp1, Ma, 0,0,0);
            Mb = __builtin_amdgcn_mfma_f32_16x16x32_bf16(afd0,  bq0, Mb, 0,0,0);
            Mb = __builtin_amdgcn_mfma_f32_16x16x32_bf16(afd1,  bq1, Mb, 0,0,0);
            Mc = __builtin_amdgcn_mfma_f32_16x16x32_bf16(afd20, bp0, Mc, 0,0,0);
            Mc = __builtin_amdgcn_mfma_f32_16x16x32_bf16(afd21, bp1, Mc, 0,0,0);

            const float w0 = sW[0][hl], w1 = sW[1][hl], w2 = sW[2][hl];
            const float w3 = sW[3][hl], w4 = sW[4][hl], bb = sW[5][hl];
            const float q0 = sW[6][hl], q1 = sW[7][hl], q2 = sW[8][hl];
            const float q3 = sW[9][hl], bq = sW[10][hl];

            const float P1 = fmaf(Ex, w0, fmaf(Ey, w1, fmaf(Ez, w2, Ew * w3)));
            const float p2h = (sP2p[0][hl] + sP2p[1][hl]) +
                              (sP2p[2][hl] + sP2p[3][hl]);
            const float p3h = (sP3p[0][hl] + sP3p[1][hl]) +
                              (sP3p[2][hl] + sP3p[3][hl]);
            const float w42 = w4 * w4, w43 = w42 * w4;
            const float tw4_3  = 3.0f * w4;       // 3 w4
            const float tw42_3 = 3.0f * w42;      // 3 w4^2
            const float b6w4   = 6.0f * w4;
            const float n3P1   = -3.0f * P1;
            const float A1     = 3.0f * p2h;
            const float diag   = fmaf(C3, bb * bb * bb, bb);

            #pragma unroll
            for (int r = 0; r < 4; ++r) {
                const float4 e = er[r];
                float pi = fmaf(e.x, w0, fmaf(e.y, w1, fmaf(e.z, w2, e.w * w3)));
                float a  = pi + bb;
                float c2 = fmaf(tw4_3, D1r[r], n3P1);
                float c1 = fmaf(tw42_3, D2r[r], A1);
                c1 = fmaf(-b6w4, Ma[r], c1);
                float c0 = fmaf(tw4_3, Mb[r], -p3h);
                c0 = fmaf(-tw42_3, Mc[r], c0);
                c0 = fmaf(w43, D3r[r], c0);
                float s3 = fmaf(fmaf(fmaf(64.0f, a, c2), a, c1), a, c0);
                float lin = fmaf(64.0f, a, fmaf(w4, D1r[r], -P1));
                float rel = fmaf(C3, s3, lin) - diag;
                float xp  = fmaf(e.x, q0, fmaf(e.y, q1,
                            fmaf(e.z, q2, fmaf(e.w, q3, bq))));
                int i = wv * 16 + quad * 4 + r;
                float* o = out + (size_t)(b * NUM_ENT + i) * (2 * HALF) + hbase;
                o[hl]        = tanh5(xp);
                o[HALF + hl] = rel;
            }
        }
    }
}

extern "C" void kernel_launch(void* const* d_in, const int* in_sizes, int n_in,
                              void* d_out, int out_size, void* d_ws, size_t ws_size,
                              hipStream_t stream) {
    const float* ctx = (const float*)d_in[0];
    const float* Wp  = (const float*)d_in[1];
    const float* bp  = (const float*)d_in[2];
    const float* Wr  = (const float*)d_in[3];
    const float* br  = (const float*)d_in[4];
    float* out = (float*)d_out;

    fused_enc<<<dim3(BATCH * 2), dim3(256), 0, stream>>>(
        ctx, Wp, bp, Wr, br, out);
}